// Round 3
// baseline (645.127 us; speedup 1.0000x reference)
//
#include <hip/hip_runtime.h>

namespace {

constexpr int L = 10000;   // links
constexpr int F = 8;       // input features
constexpr int H = 64;      // hidden size
constexpr int B = 32;      // batch

__device__ __forceinline__ float fsigmoid(float x) {
    return 1.0f / (1.0f + __expf(-x));
}
__device__ __forceinline__ float ftanh(float x) {
    return 2.0f / (1.0f + __expf(-2.0f * x)) - 1.0f;
}

// 24 FMAs: one i-step for both b's and 4 k's, all components explicit.
#define GATE_FMA(xx, wr, wu, wn)                                          \
    do {                                                                  \
        accR[0][0] += (xx).x * (wr).x; accR[0][1] += (xx).x * (wr).y;     \
        accR[0][2] += (xx).x * (wr).z; accR[0][3] += (xx).x * (wr).w;     \
        accR[1][0] += (xx).y * (wr).x; accR[1][1] += (xx).y * (wr).y;     \
        accR[1][2] += (xx).y * (wr).z; accR[1][3] += (xx).y * (wr).w;     \
        accU[0][0] += (xx).x * (wu).x; accU[0][1] += (xx).x * (wu).y;     \
        accU[0][2] += (xx).x * (wu).z; accU[0][3] += (xx).x * (wu).w;     \
        accU[1][0] += (xx).y * (wu).x; accU[1][1] += (xx).y * (wu).y;     \
        accU[1][2] += (xx).y * (wu).z; accU[1][3] += (xx).y * (wu).w;     \
        accN[0][0] += (xx).x * (wn).x; accN[0][1] += (xx).x * (wn).y;     \
        accN[0][2] += (xx).x * (wn).z; accN[0][3] += (xx).x * (wn).w;     \
        accN[1][0] += (xx).y * (wn).x; accN[1][1] += (xx).y * (wn).y;     \
        accN[1][2] += (xx).y * (wn).z; accN[1][3] += (xx).y * (wn).w;     \
    } while (0)

#define GATE_FMA_IN(xx, wr, wu, wn)                                       \
    do {                                                                  \
        accR[0][0] += (xx).x * (wr).x; accR[0][1] += (xx).x * (wr).y;     \
        accR[0][2] += (xx).x * (wr).z; accR[0][3] += (xx).x * (wr).w;     \
        accR[1][0] += (xx).y * (wr).x; accR[1][1] += (xx).y * (wr).y;     \
        accR[1][2] += (xx).y * (wr).z; accR[1][3] += (xx).y * (wr).w;     \
        accU[0][0] += (xx).x * (wu).x; accU[0][1] += (xx).x * (wu).y;     \
        accU[0][2] += (xx).x * (wu).z; accU[0][3] += (xx).x * (wu).w;     \
        accU[1][0] += (xx).y * (wu).x; accU[1][1] += (xx).y * (wu).y;     \
        accU[1][2] += (xx).y * (wu).z; accU[1][3] += (xx).y * (wu).w;     \
        accNI[0][0] += (xx).x * (wn).x; accNI[0][1] += (xx).x * (wn).y;   \
        accNI[0][2] += (xx).x * (wn).z; accNI[0][3] += (xx).x * (wn).w;   \
        accNI[1][0] += (xx).y * (wn).x; accNI[1][1] += (xx).y * (wn).y;   \
        accNI[1][2] += (xx).y * (wn).z; accNI[1][3] += (xx).y * (wn).w;   \
    } while (0)

__global__ __launch_bounds__(256, 4)
void gcrnn_cell(const float* __restrict__ hidden, const float* __restrict__ xin,
                const float* __restrict__ Wrh, const float* __restrict__ Brh,
                const float* __restrict__ Wri, const float* __restrict__ Bri,
                const float* __restrict__ Wuh, const float* __restrict__ Buh,
                const float* __restrict__ Wui, const float* __restrict__ Bui,
                const float* __restrict__ Wnh, const float* __restrict__ Bnh,
                const float* __restrict__ Wni, const float* __restrict__ Bni,
                float* __restrict__ out)
{
    // XCD-chunked bijective swizzle: consecutive j on one XCD's L2.
    const int bid = blockIdx.x;
    const int j = (bid & 7) * (L / 8) + (bid >> 3);

    __shared__ __align__(16) float sXh[H][B];    // [i][b]
    __shared__ __align__(16) float sXi[F][B];

    const int t = threadIdx.x;
    const int kq = t & 15;         // k0 = kq*4 : thread owns 4 contiguous k
    const int k0 = kq * 4;
    const int b0 = (t >> 4) * 2;   // thread owns 2 contiguous b

    // ---- stage activations (scattered 4B; adjacent-j blocks share L2 lines)
#pragma unroll
    for (int n = 0; n < (H * B) / 256; ++n) {
        const int idx = t + 256 * n;
        sXh[idx >> 5][idx & 31] = hidden[(size_t)((idx & 31) * H + (idx >> 5)) * L + j];
    }
    sXi[t >> 5][t & 31] = xin[(size_t)((t & 31) * F + (t >> 5)) * L + j];

    // ---- biases early (latency overlaps GEMM)
    float bR[4], bU[4], bNH[4], bNI[4];
#pragma unroll
    for (int kk = 0; kk < 4; ++kk) {
        const size_t o = (size_t)(k0 + kk) * L + j;
        bR[kk]  = Brh[o] + Bri[o];
        bU[kk]  = Buh[o] + Bui[o];
        bNH[kk] = Bnh[o];
        bNI[kk] = Bni[o];
    }

    // weight row base: row i, this thread's quad at [i*16 + kq]
    const float4* pR = (const float4*)(Wrh + (size_t)j * H * H) + kq;
    const float4* pU = (const float4*)(Wuh + (size_t)j * H * H) + kq;
    const float4* pN = (const float4*)(Wnh + (size_t)j * H * H) + kq;
    const float4* qR = (const float4*)(Wri + (size_t)j * F * H) + kq;
    const float4* qU = (const float4*)(Wui + (size_t)j * F * H) + kq;
    const float4* qN = (const float4*)(Wni + (size_t)j * F * H) + kq;

    float accR[2][4] = {};
    float accU[2][4] = {};
    float accN[2][4] = {};
    float accNI[2][4] = {};

    // prime the software pipeline BEFORE the barrier (loads independent of LDS)
    float4 cR0 = pR[0 * 16], cU0 = pU[0 * 16], cN0 = pN[0 * 16];
    float4 cR1 = pR[1 * 16], cU1 = pU[1 * 16], cN1 = pN[1 * 16];

    __syncthreads();

    // ---- input GEMM (K=8), small: simple loop
#pragma unroll 2
    for (int i = 0; i < F; ++i) {
        const float4 wr = qR[i * 16];
        const float4 wu = qU[i * 16];
        const float4 wn = qN[i * 16];
        const float2 x = *(const float2*)&sXi[i][b0];
        GATE_FMA_IN(x, wr, wu, wn);
    }

    // ---- hidden GEMM (K=64), explicit depth-2 (pair-ahead) software pipeline
#pragma unroll 4
    for (int i = 0; i < H; i += 2) {
        const int ip = (i + 2) & (H - 1);   // wraps to row 0 on last iter (harmless)
        float4 nR0 = pR[ip * 16],       nU0 = pU[ip * 16],       nN0 = pN[ip * 16];
        float4 nR1 = pR[(ip + 1) * 16], nU1 = pU[(ip + 1) * 16], nN1 = pN[(ip + 1) * 16];

        const float2 x0 = *(const float2*)&sXh[i][b0];
        const float2 x1 = *(const float2*)&sXh[i + 1][b0];
        GATE_FMA(x0, cR0, cU0, cN0);
        GATE_FMA(x1, cR1, cU1, cN1);

        cR0 = nR0; cU0 = nU0; cN0 = nN0;
        cR1 = nR1; cU1 = nU1; cN1 = nN1;
    }

    // ---- epilogue
#pragma unroll
    for (int b = 0; b < 2; ++b) {
#pragma unroll
        for (int kk = 0; kk < 4; ++kk) {
            const int k = k0 + kk;
            const float r = fsigmoid(accR[b][kk] + bR[kk]);
            const float u = fsigmoid(accU[b][kk] + bU[kk]);
            const float n = ftanh(r * (accN[b][kk] + bNH[kk]) + accNI[b][kk] + bNI[kk]);
            const float h = sXh[k][b0 + b];
            out[(size_t)((b0 + b) * H + k) * L + j] = (1.0f - u) * n + u * h;
        }
    }
}

} // namespace

extern "C" void kernel_launch(void* const* d_in, const int* in_sizes, int n_in,
                              void* d_out, int out_size, void* d_ws, size_t ws_size,
                              hipStream_t stream) {
    const float* hidden = (const float*)d_in[0];
    const float* xin    = (const float*)d_in[1];
    const float* Wrh    = (const float*)d_in[2];
    const float* Brh    = (const float*)d_in[3];
    const float* Wri    = (const float*)d_in[4];
    const float* Bri    = (const float*)d_in[5];
    const float* Wuh    = (const float*)d_in[6];
    const float* Buh    = (const float*)d_in[7];
    const float* Wui    = (const float*)d_in[8];
    const float* Bui    = (const float*)d_in[9];
    const float* Wnh    = (const float*)d_in[10];
    const float* Bnh    = (const float*)d_in[11];
    const float* Wni    = (const float*)d_in[12];
    const float* Bni    = (const float*)d_in[13];
    float* out = (float*)d_out;

    gcrnn_cell<<<L, 256, 0, stream>>>(hidden, xin,
                                      Wrh, Brh, Wri, Bri,
                                      Wuh, Buh, Wui, Bui,
                                      Wnh, Bnh, Wni, Bni,
                                      out);
}

// Round 4
// 447.179 us; speedup vs baseline: 1.4427x; 1.4427x over previous
//
#include <hip/hip_runtime.h>

namespace {

constexpr int L = 10000;   // links
constexpr int F = 8;       // input features
constexpr int H = 64;      // hidden size
constexpr int NB = 32;     // batch

typedef __bf16 bf16x8 __attribute__((ext_vector_type(8)));
typedef float  f32x4  __attribute__((ext_vector_type(4)));

__device__ __forceinline__ float fsigmoid(float x) {
    return 1.0f / (1.0f + __expf(-x));
}
__device__ __forceinline__ float ftanh(float x) {
    return 2.0f / (1.0f + __expf(-2.0f * x)) - 1.0f;
}

// One wave per link. MFMA 16x16x32 bf16: A = Xh (32x64), B = W (64x64).
// A-frag: lane holds A[row=lane&15][k=(lane>>4)*8+e]
// B-frag: lane holds B[k=(lane>>4)*8+e][col=lane&15]
// D: col=lane&15, row=(lane>>4)*4+reg   [guide-verified m89]
__global__ __launch_bounds__(256, 2)
void gcrnn_mfma(const float* __restrict__ hidden, const float* __restrict__ xin,
                const float* __restrict__ Wrh, const float* __restrict__ Brh,
                const float* __restrict__ Wri, const float* __restrict__ Bri,
                const float* __restrict__ Wuh, const float* __restrict__ Buh,
                const float* __restrict__ Wui, const float* __restrict__ Bui,
                const float* __restrict__ Wnh, const float* __restrict__ Bnh,
                const float* __restrict__ Wni, const float* __restrict__ Bni,
                float* __restrict__ out)
{
    // bijective XCD-chunked swizzle over 2500 workgroups (4 links each):
    // consecutive j live on one XCD -> scattered per-j lines L2-shared.
    constexpr int NWG = L / 4;                 // 2500
    constexpr int q = NWG / 8, r = NWG % 8;    // 312, 4
    const int orig = blockIdx.x;
    const int xcd = orig & 7, idx = orig >> 3;
    const int wg = (xcd < r ? xcd * (q + 1) : r * (q + 1) + (xcd - r) * q) + idx;

    const int lane = threadIdx.x & 63;
    const int wid  = threadIdx.x >> 6;
    const int j    = wg * 4 + wid;             // this wave's link

    const int lc  = lane & 15;                 // A-row / B-col / D-col
    const int grp = lane >> 4;                 // 0..3

    // ---- A fragments: Xh [m][ks], Xi [m] (K=32 padded: only k<8 real)
    bf16x8 aH[2][2];
    bf16x8 aI[2];
#pragma unroll
    for (int m = 0; m < 2; ++m) {
        const int b_ = m * 16 + lc;
        const size_t base = (size_t)b_ * H * L + j;
#pragma unroll
        for (int ks = 0; ks < 2; ++ks) {
#pragma unroll
            for (int e = 0; e < 8; ++e) {
                const int i = ks * 32 + grp * 8 + e;
                aH[m][ks][e] = (__bf16)hidden[base + (size_t)i * L];
            }
        }
        const size_t ibase = (size_t)b_ * F * L + j;
#pragma unroll
        for (int e = 0; e < 8; ++e) {
            float v = 0.0f;
            if (grp == 0) v = xin[ibase + (size_t)e * L];
            aI[m][e] = (__bf16)v;
        }
    }

    const float* WR = Wrh + (size_t)j * H * H;
    const float* WU = Wuh + (size_t)j * H * H;
    const float* WN = Wnh + (size_t)j * H * H;
    const float* IR = Wri + (size_t)j * F * H;
    const float* IU = Wui + (size_t)j * F * H;
    const float* IN = Wni + (size_t)j * F * H;

    for (int n = 0; n < 4; ++n) {
        const int col = n * 16 + lc;

        // ---- B fragments from global f32 (each weight byte read once), cvt bf16
        bf16x8 bR[2], bU[2], bN[2];
#pragma unroll
        for (int ks = 0; ks < 2; ++ks) {
#pragma unroll
            for (int e = 0; e < 8; ++e) {
                const int i = ks * 32 + grp * 8 + e;
                bR[ks][e] = (__bf16)WR[i * H + col];
                bU[ks][e] = (__bf16)WU[i * H + col];
                bN[ks][e] = (__bf16)WN[i * H + col];
            }
        }
        bf16x8 iR, iU, iN;
#pragma unroll
        for (int e = 0; e < 8; ++e) {
            float vr = 0.0f, vu = 0.0f, vn = 0.0f;
            if (grp == 0) {
                vr = IR[e * H + col];
                vu = IU[e * H + col];
                vn = IN[e * H + col];
            }
            iR[e] = (__bf16)vr; iU[e] = (__bf16)vu; iN[e] = (__bf16)vn;
        }

        // ---- biases + passthrough h issued early (overlap MFMAs)
        const size_t ko = (size_t)col * L + j;
        const float biR  = Brh[ko] + Bri[ko];
        const float biU  = Buh[ko] + Bui[ko];
        const float biNH = Bnh[ko];
        const float biNI = Bni[ko];
        float hpass[2][4];
#pragma unroll
        for (int m = 0; m < 2; ++m)
#pragma unroll
            for (int rr = 0; rr < 4; ++rr) {
                const int b_ = m * 16 + grp * 4 + rr;
                hpass[m][rr] = hidden[((size_t)b_ * H + col) * L + j];
            }

        // ---- MFMAs: 4 gate-accumulators x 2 m-tiles
        f32x4 accR[2], accU[2], accN[2], accNI[2];
#pragma unroll
        for (int m = 0; m < 2; ++m) {
            accR[m] = (f32x4){0.f, 0.f, 0.f, 0.f};
            accU[m] = (f32x4){0.f, 0.f, 0.f, 0.f};
            accN[m] = (f32x4){0.f, 0.f, 0.f, 0.f};
            accNI[m] = (f32x4){0.f, 0.f, 0.f, 0.f};
#pragma unroll
            for (int ks = 0; ks < 2; ++ks) {
                accR[m] = __builtin_amdgcn_mfma_f32_16x16x32_bf16(aH[m][ks], bR[ks], accR[m], 0, 0, 0);
                accU[m] = __builtin_amdgcn_mfma_f32_16x16x32_bf16(aH[m][ks], bU[ks], accU[m], 0, 0, 0);
                accN[m] = __builtin_amdgcn_mfma_f32_16x16x32_bf16(aH[m][ks], bN[ks], accN[m], 0, 0, 0);
            }
            accR[m]  = __builtin_amdgcn_mfma_f32_16x16x32_bf16(aI[m], iR, accR[m], 0, 0, 0);
            accU[m]  = __builtin_amdgcn_mfma_f32_16x16x32_bf16(aI[m], iU, accU[m], 0, 0, 0);
            accNI[m] = __builtin_amdgcn_mfma_f32_16x16x32_bf16(aI[m], iN, accNI[m], 0, 0, 0);
        }

        // ---- epilogue + store (D layout: row = grp*4+rr, col = n*16+lc)
#pragma unroll
        for (int m = 0; m < 2; ++m)
#pragma unroll
            for (int rr = 0; rr < 4; ++rr) {
                const int b_ = m * 16 + grp * 4 + rr;
                const float rv = fsigmoid(accR[m][rr] + biR);
                const float uv = fsigmoid(accU[m][rr] + biU);
                const float nv = ftanh(rv * (accN[m][rr] + biNH) + accNI[m][rr] + biNI);
                out[((size_t)b_ * H + col) * L + j] =
                    (1.0f - uv) * nv + uv * hpass[m][rr];
            }
    }
}

} // namespace

extern "C" void kernel_launch(void* const* d_in, const int* in_sizes, int n_in,
                              void* d_out, int out_size, void* d_ws, size_t ws_size,
                              hipStream_t stream) {
    const float* hidden = (const float*)d_in[0];
    const float* xin    = (const float*)d_in[1];
    const float* Wrh    = (const float*)d_in[2];
    const float* Brh    = (const float*)d_in[3];
    const float* Wri    = (const float*)d_in[4];
    const float* Bri    = (const float*)d_in[5];
    const float* Wuh    = (const float*)d_in[6];
    const float* Buh    = (const float*)d_in[7];
    const float* Wui    = (const float*)d_in[8];
    const float* Bui    = (const float*)d_in[9];
    const float* Wnh    = (const float*)d_in[10];
    const float* Bnh    = (const float*)d_in[11];
    const float* Wni    = (const float*)d_in[12];
    const float* Bni    = (const float*)d_in[13];
    float* out = (float*)d_out;

    gcrnn_mfma<<<L / 4, 256, 0, stream>>>(hidden, xin,
                                          Wrh, Brh, Wri, Bri,
                                          Wuh, Buh, Wui, Bui,
                                          Wnh, Bnh, Wni, Bni,
                                          out);
}

// Round 5
// 371.821 us; speedup vs baseline: 1.7350x; 1.2027x over previous
//
#include <hip/hip_runtime.h>

namespace {

constexpr int L = 10000;   // links
constexpr int F = 8;       // input features
constexpr int H = 64;      // hidden size

typedef __bf16 bf16x8 __attribute__((ext_vector_type(8)));
typedef float  f32x4  __attribute__((ext_vector_type(4)));

__device__ __forceinline__ float fsigmoid(float x) {
    return 1.0f / (1.0f + __expf(-x));
}
__device__ __forceinline__ float ftanh(float x) {
    return 2.0f / (1.0f + __expf(-2.0f * x)) - 1.0f;
}

// LDS layouts (f32 words):
//  sXh: [jl][i=64][b=32] word = jl*2112 + i*33 + b   (stride 33: A-frag reads
//       2-way free; also reused IN PLACE for h-pass read + out staging)
//  sXi: [jl][i=8][b=32]  word = jl*264 + i*33 + b
//  sB : [s=4][jl][col]   word = s*256 + jl*64 + col  (s: R,U,NH,NI; R/U biases
//       pre-combined at staging)
constexpr int XH_LINK = 64 * 33;   // 2112
constexpr int XI_LINK = 8 * 33;    // 264

// One wave per link. MFMA 16x16x32 bf16.
// A-frag: lane holds A[row=lane&15][k=(lane>>4)*8+e]
// B-frag: lane holds B[k=(lane>>4)*8+e][col=lane&15]
// D: col=lane&15, row=(lane>>4)*4+reg   [guide-verified m89]
__global__ __launch_bounds__(256, 3)
void gcrnn_mfma(const float* __restrict__ hidden, const float* __restrict__ xin,
                const float* __restrict__ Wrh, const float* __restrict__ Brh,
                const float* __restrict__ Wri, const float* __restrict__ Bri,
                const float* __restrict__ Wuh, const float* __restrict__ Buh,
                const float* __restrict__ Wui, const float* __restrict__ Bui,
                const float* __restrict__ Wnh, const float* __restrict__ Bnh,
                const float* __restrict__ Wni, const float* __restrict__ Bni,
                float* __restrict__ out)
{
    // bijective XCD-chunked swizzle over 2500 workgroups (4 links each)
    constexpr int NWG = L / 4;                 // 2500
    constexpr int q = NWG / 8, r = NWG % 8;    // 312, 4
    const int orig = blockIdx.x;
    const int xcd = orig & 7, idx = orig >> 3;
    const int wg = (xcd < r ? xcd * (q + 1) : r * (q + 1) + (xcd - r) * q) + idx;
    const int j0 = wg * 4;

    __shared__ float sXh[4 * XH_LINK];   // 33.8 KB
    __shared__ float sXi[4 * XI_LINK];   // 4.2 KB
    __shared__ float sB[4 * 256];        // 4.0 KB

    const int tb = threadIdx.x;

    // ================= cooperative staging (16B-segment coalesced) ==========
    {
        const int jl = tb & 3;
        const int rq = tb >> 2;            // 0..63
        // Xh: row f = c*64 + rq  ->  b = c, i = rq
#pragma unroll 4
        for (int c = 0; c < 32; ++c) {
            sXh[jl * XH_LINK + rq * 33 + c] =
                hidden[(size_t)(c * 64 + rq) * L + j0 + jl];
        }
        // Xi: 256 rows (b*8+i) x 4 j
#pragma unroll
        for (int c = 0; c < 4; ++c) {
            const int rr = c * 64 + rq;
            const int b = rr >> 3, i = rr & 7;
            sXi[jl * XI_LINK + i * 33 + b] =
                xin[(size_t)(b * F + i) * L + j0 + jl];
        }
        // bias (col = rq), R/U pre-combined
        const size_t o = (size_t)rq * L + j0 + jl;
        sB[0 * 256 + jl * 64 + rq] = Brh[o] + Bri[o];
        sB[1 * 256 + jl * 64 + rq] = Buh[o] + Bui[o];
        sB[2 * 256 + jl * 64 + rq] = Bnh[o];
        sB[3 * 256 + jl * 64 + rq] = Bni[o];
    }
    __syncthreads();

    // ================= per-wave per-link MFMA ================================
    const int lane = tb & 63;
    const int jl   = tb >> 6;              // wave owns link jl
    const int j    = j0 + jl;
    const int lc   = lane & 15;
    const int grp  = lane >> 4;

    // A fragments from LDS (2-way bank access = free)
    bf16x8 aH[2][2];
    bf16x8 aI[2];
#pragma unroll
    for (int m = 0; m < 2; ++m) {
        const int b_ = m * 16 + lc;
#pragma unroll
        for (int ks = 0; ks < 2; ++ks)
#pragma unroll
            for (int e = 0; e < 8; ++e)
                aH[m][ks][e] = (__bf16)sXh[jl * XH_LINK + (ks * 32 + grp * 8 + e) * 33 + b_];
#pragma unroll
        for (int e = 0; e < 8; ++e) {
            float v = (grp == 0) ? sXi[jl * XI_LINK + e * 33 + b_] : 0.0f;
            aI[m][e] = (__bf16)v;
        }
    }

    const float* WR = Wrh + (size_t)j * H * H;
    const float* WU = Wuh + (size_t)j * H * H;
    const float* WN = Wnh + (size_t)j * H * H;
    const float* IR = Wri + (size_t)j * F * H;
    const float* IU = Wui + (size_t)j * F * H;
    const float* IN = Wni + (size_t)j * F * H;

#pragma unroll
    for (int n = 0; n < 4; ++n) {
        const int col = n * 16 + lc;

        // B fragments straight from global f32 (4x64B segments per instr)
        bf16x8 bR[2], bU[2], bN[2];
#pragma unroll
        for (int ks = 0; ks < 2; ++ks)
#pragma unroll
            for (int e = 0; e < 8; ++e) {
                const int i = ks * 32 + grp * 8 + e;
                bR[ks][e] = (__bf16)WR[i * H + col];
                bU[ks][e] = (__bf16)WU[i * H + col];
                bN[ks][e] = (__bf16)WN[i * H + col];
            }
        bf16x8 iR, iU, iN;
#pragma unroll
        for (int e = 0; e < 8; ++e) {
            float vr = 0.0f, vu = 0.0f, vn = 0.0f;
            if (grp == 0) {
                vr = IR[e * H + col];
                vu = IU[e * H + col];
                vn = IN[e * H + col];
            }
            iR[e] = (__bf16)vr; iU[e] = (__bf16)vu; iN[e] = (__bf16)vn;
        }

        // biases from LDS (broadcast)
        const float biR  = sB[0 * 256 + jl * 64 + col];
        const float biU  = sB[1 * 256 + jl * 64 + col];
        const float biNH = sB[2 * 256 + jl * 64 + col];
        const float biNI = sB[3 * 256 + jl * 64 + col];

        // MFMAs: 4 gate accumulators x 2 m-tiles
        f32x4 accR[2], accU[2], accN[2], accNI[2];
#pragma unroll
        for (int m = 0; m < 2; ++m) {
            accR[m] = (f32x4){0.f, 0.f, 0.f, 0.f};
            accU[m] = (f32x4){0.f, 0.f, 0.f, 0.f};
            accN[m] = (f32x4){0.f, 0.f, 0.f, 0.f};
            accNI[m] = (f32x4){0.f, 0.f, 0.f, 0.f};
#pragma unroll
            for (int ks = 0; ks < 2; ++ks) {
                accR[m] = __builtin_amdgcn_mfma_f32_16x16x32_bf16(aH[m][ks], bR[ks], accR[m], 0, 0, 0);
                accU[m] = __builtin_amdgcn_mfma_f32_16x16x32_bf16(aH[m][ks], bU[ks], accU[m], 0, 0, 0);
                accN[m] = __builtin_amdgcn_mfma_f32_16x16x32_bf16(aH[m][ks], bN[ks], accN[m], 0, 0, 0);
            }
            accR[m]  = __builtin_amdgcn_mfma_f32_16x16x32_bf16(aI[m], iR, accR[m], 0, 0, 0);
            accU[m]  = __builtin_amdgcn_mfma_f32_16x16x32_bf16(aI[m], iU, accU[m], 0, 0, 0);
            accNI[m] = __builtin_amdgcn_mfma_f32_16x16x32_bf16(aI[m], iN, accNI[m], 0, 0, 0);
        }

        // epilogue: read h from LDS word (col*33+b_), write out to SAME word
        // (register dependency orders read-before-write; column jl is wave-private)
#pragma unroll
        for (int m = 0; m < 2; ++m)
#pragma unroll
            for (int rr = 0; rr < 4; ++rr) {
                const int b_ = m * 16 + grp * 4 + rr;
                const int w = jl * XH_LINK + col * 33 + b_;
                const float h = sXh[w];
                const float rv = fsigmoid(accR[m][rr] + biR);
                const float uv = fsigmoid(accU[m][rr] + biU);
                const float nv = ftanh(rv * (accN[m][rr] + biNH) + accNI[m][rr] + biNI);
                sXh[w] = (1.0f - uv) * nv + uv * h;
            }
    }

    __syncthreads();

    // ================= cooperative coalesced writeout ========================
    {
        const int jl2 = tb & 3;
        const int rq = tb >> 2;            // k = rq
#pragma unroll 4
        for (int c = 0; c < 32; ++c) {     // b = c
            out[(size_t)(c * 64 + rq) * L + j0 + jl2] =
                sXh[jl2 * XH_LINK + rq * 33 + c];
        }
    }
}

} // namespace

extern "C" void kernel_launch(void* const* d_in, const int* in_sizes, int n_in,
                              void* d_out, int out_size, void* d_ws, size_t ws_size,
                              hipStream_t stream) {
    const float* hidden = (const float*)d_in[0];
    const float* xin    = (const float*)d_in[1];
    const float* Wrh    = (const float*)d_in[2];
    const float* Brh    = (const float*)d_in[3];
    const float* Wri    = (const float*)d_in[4];
    const float* Bri    = (const float*)d_in[5];
    const float* Wuh    = (const float*)d_in[6];
    const float* Buh    = (const float*)d_in[7];
    const float* Wui    = (const float*)d_in[8];
    const float* Bui    = (const float*)d_in[9];
    const float* Wnh    = (const float*)d_in[10];
    const float* Bnh    = (const float*)d_in[11];
    const float* Wni    = (const float*)d_in[12];
    const float* Bni    = (const float*)d_in[13];
    float* out = (float*)d_out;

    gcrnn_mfma<<<L / 4, 256, 0, stream>>>(hidden, xin,
                                          Wrh, Brh, Wri, Bri,
                                          Wuh, Buh, Wui, Bui,
                                          Wnh, Bnh, Wni, Bni,
                                          out);
}